// Round 13
// baseline (1054.168 us; speedup 1.0000x reference)
//
#include <hip/hip_runtime.h>
#include <hip/hip_bf16.h>

// SetAbstraction: FPS -> kNN(32) -> gather -> 3x(conv1x1+BN+ReLU) -> maxpool(K)
// B=16 N=4096 S=1024 K=32 D_IN=64 MLP=[64,64,128]
// Layer-1 decomposed: z1[s,k] = P[idx[s,k]] - Q[s]
//   P[n] = W1a·pts[n] + W1b·xyz[n] + b1  (computed inside fused kernel's
//          transpose blocks, hidden under FPS)   Q[s] = W1b·new_xyz[s]

typedef __attribute__((ext_vector_type(8))) short bfrag;    // 8 bf16 (MFMA A/B)
typedef __attribute__((ext_vector_type(4))) float ffrag;    // 4 f32 (MFMA C/D)
typedef __attribute__((ext_vector_type(8))) unsigned short ushort8;

#define XS 104   // LDS row stride in bf16 elems (gemm kernels)

__device__ inline unsigned short f2bf(float f){
  union { float f; unsigned u; } v; v.f = f;
  unsigned r = v.u + 0x7fffu + ((v.u >> 16) & 1u);   // RNE
  return (unsigned short)(r >> 16);
}
__device__ inline float bf2f(unsigned short h){
  union { unsigned u; float f; } v; v.u = ((unsigned)h) << 16; return v.f;
}
// shared by P-epilogue and Q so identical inputs cancel exactly in P-Q
__device__ __forceinline__ float dot3(float wx, float wy, float wz, float x, float y, float z){
  return __fadd_rn(__fadd_rn(__fmul_rn(wx, x), __fmul_rn(wy, y)), __fmul_rn(wz, z));
}

// ---- DPP cross-lane (VALU-rate; no LDS pipe)
template<int CTRL> __device__ __forceinline__ int dppi(int v){
  return __builtin_amdgcn_update_dpp(0, v, CTRL, 0xF, 0xF, true);
}
template<int CTRL> __device__ __forceinline__ float dppf(float v){
  return __int_as_float(dppi<CTRL>(__float_as_int(v)));
}
__device__ __forceinline__ float dppmax6(float v){   // lane63 = wave max
  v = fmaxf(v, dppf<0xB1>(v)); v = fmaxf(v, dppf<0x4E>(v));
  v = fmaxf(v, dppf<0x141>(v)); v = fmaxf(v, dppf<0x140>(v));
  v = fmaxf(v, dppf<0x142>(v)); v = fmaxf(v, dppf<0x143>(v));
  return v;
}
__device__ __forceinline__ float dppmin6(float v){   // lane63 = wave min
  v = fminf(v, dppf<0xB1>(v)); v = fminf(v, dppf<0x4E>(v));
  v = fminf(v, dppf<0x141>(v)); v = fminf(v, dppf<0x140>(v));
  v = fminf(v, dppf<0x142>(v)); v = fminf(v, dppf<0x143>(v));
  return v;
}
__device__ __forceinline__ unsigned dppminu6(unsigned v){
  unsigned o;
  o = (unsigned)dppi<0xB1>((int)v);  v = v < o ? v : o;
  o = (unsigned)dppi<0x4E>((int)v);  v = v < o ? v : o;
  o = (unsigned)dppi<0x141>((int)v); v = v < o ? v : o;
  o = (unsigned)dppi<0x140>((int)v); v = v < o ? v : o;
  o = (unsigned)dppi<0x142>((int)v); v = v < o ? v : o;
  o = (unsigned)dppi<0x143>((int)v); v = v < o ? v : o;
  return v;                                          // lane63 = wave min
}
__device__ __forceinline__ float dppadd4(float v){   // all lanes: 16-lane-row sum
  v += dppf<0xB1>(v); v += dppf<0x4E>(v); v += dppf<0x141>(v); v += dppf<0x140>(v);
  return v;
}
__device__ __forceinline__ float dppmax4(float v){
  v = fmaxf(v, dppf<0xB1>(v)); v = fmaxf(v, dppf<0x4E>(v));
  v = fmaxf(v, dppf<0x141>(v)); v = fmaxf(v, dppf<0x140>(v));
  return v;
}
__device__ __forceinline__ float dppmin4(float v){
  v = fminf(v, dppf<0xB1>(v)); v = fminf(v, dppf<0x4E>(v));
  v = fminf(v, dppf<0x141>(v)); v = fminf(v, dppf<0x140>(v));
  return v;
}

// ---------------- wconv: W -> bf16 (Wb1 padded 67->96) + zero stats (replaces memset)
__global__ __launch_bounds__(256) void wconv_k(const float* __restrict__ W1,
    const float* __restrict__ W2, const float* __restrict__ W3,
    unsigned short* __restrict__ Wb1, unsigned short* __restrict__ Wb2,
    unsigned short* __restrict__ Wb3, float* __restrict__ stats){
  const int t = threadIdx.x;
  for (int i = t; i < 64 * 96; i += 256){
    int r = i / 96, c = i % 96;
    Wb1[i] = (c < 67) ? f2bf(W1[r * 67 + c]) : (unsigned short)0;
  }
  for (int i = t; i < 64 * 64; i += 256) Wb2[i] = f2bf(W2[i]);
  for (int i = t; i < 128 * 64; i += 256) Wb3[i] = f2bf(W3[i]);
  for (int i = t; i < 32768; i += 256) stats[i] = 0.f;
}

// ---------------- fused FPS (blocks 0..15) + transpose+P (blocks 16..271), 512 thr.
// FPS: R8-proven config — single u64 ring slot, t0 reset, 8 pts/thr.
// Transpose blocks: load pts tile [64ch][256n] -> LDS, xyz -> LDS, then MFMA
// P[n][o] = W1a·pts + b1 + W1b·xyz directly (pts_t / xyz_t eliminated).
// These 256 blocks run on the 240 non-FPS CUs, hidden under FPS.
__global__ __launch_bounds__(512) void fused_fps_tr_k(const float* __restrict__ xyz,
    const float* __restrict__ pts, float* __restrict__ out0, float* __restrict__ new_xyz,
    const unsigned short* __restrict__ Wb1, const float* __restrict__ b1,
    float* __restrict__ P){
  __shared__ __align__(16) char smem[65536 + 32 + 2048];
  const int t = threadIdx.x, bid = blockIdx.x;
  if (bid >= 16){
    // ---------------- transpose+P path (512 thr, 8 waves x 32 cols) ----------------
    unsigned short* tile = (unsigned short*)smem;            // 64*258*2 = 33024 B
    float* xs = (float*)(smem + 40960);                      // 256 f32
    float* ys = xs + 256;
    float* zs = ys + 256;
    const int bid2 = bid - 16;
    const int b = bid2 >> 4, n0 = (bid2 & 15) * 256;
    {
      const int n = t & 255, ch = t >> 8;                    // ch in {0,1}
      for (int it = 0; it < 32; it++){
        int c = it * 2 + ch;
        tile[c * 258 + n] = f2bf(pts[((size_t)(b * 64 + c)) * 4096 + n0 + n]);
      }
    }
    if (t < 256){
      xs[t] = xyz[((size_t)(b * 3 + 0)) * 4096 + n0 + t];
      ys[t] = xyz[((size_t)(b * 3 + 1)) * 4096 + n0 + t];
      zs[t] = xyz[((size_t)(b * 3 + 2)) * 4096 + n0 + t];
    }
    const int lane = t & 63, lr = lane & 15, lg = lane >> 4;
    const int colw = (t >> 6) * 32;                          // 8 waves x 32 cols
    bfrag a[4][2];
    #pragma unroll
    for (int r = 0; r < 4; r++)
      #pragma unroll
      for (int kk = 0; kk < 2; kk++)
        a[r][kk] = *(const bfrag*)&Wb1[(16 * r + lr) * 96 + kk * 32 + lg * 8];
    __syncthreads();
    ffrag acc[4][2] = {};
    #pragma unroll
    for (int kk = 0; kk < 2; kk++){
      bfrag bb[2];
      #pragma unroll
      for (int cf = 0; cf < 2; cf++){
        const int nL = colw + cf * 16 + lr;
        #pragma unroll
        for (int e = 0; e < 8; e++)
          bb[cf][e] = (short)tile[(kk * 32 + lg * 8 + e) * 258 + nL];
      }
      #pragma unroll
      for (int r = 0; r < 4; r++)
        #pragma unroll
        for (int cf = 0; cf < 2; cf++)
          acc[r][cf] = __builtin_amdgcn_mfma_f32_16x16x32_bf16(a[r][kk], bb[cf], acc[r][cf], 0, 0, 0);
    }
    #pragma unroll
    for (int r = 0; r < 4; r++){
      const int o0 = 16 * r + 4 * lg;
      const ffrag bv = *(const ffrag*)&b1[o0];
      float wx[4], wy[4], wz[4];
      #pragma unroll
      for (int e = 0; e < 4; e++){
        wx[e] = bf2f(Wb1[(o0 + e) * 96 + 64]);
        wy[e] = bf2f(Wb1[(o0 + e) * 96 + 65]);
        wz[e] = bf2f(Wb1[(o0 + e) * 96 + 66]);
      }
      #pragma unroll
      for (int cf = 0; cf < 2; cf++){
        const int nL = colw + cf * 16 + lr;
        const float gx = xs[nL], gy = ys[nL], gz = zs[nL];
        ffrag out;
        #pragma unroll
        for (int e = 0; e < 4; e++)
          out[e] = __fadd_rn(__fadd_rn(acc[r][cf][e], bv[e]),
                             dot3(wx[e], wy[e], wz[e], gx, gy, gz));
        *(ffrag*)&P[(((size_t)(b * 4096) + n0 + nL) * 64 + o0)] = out;
      }
    }
    return;
  }
  // ---------------- FPS path (512 thr, 8 pts/thr) ----------------
  float4* xl4 = (float4*)smem;                               // 65536 B
  unsigned long long* skey = (unsigned long long*)(smem + 65536);   // 32 B
  unsigned short* farhist = (unsigned short*)(smem + 65568);        // 2048 B
  const int b = bid;
  {
    const float* xb = xyz + (size_t)b * 3 * 4096;
    for (int j = 0; j < 8; j++){
      int i = j * 512 + t;
      float4 v; v.x = xb[i]; v.y = xb[4096 + i]; v.z = xb[8192 + i]; v.w = 0.f;
      xl4[i] = v;
    }
  }
  if (t == 0){
    skey[0] = 0xFFFFFFFF00000FFFull;   // lo=4095 -> far=0
    skey[1] = 0ull; skey[2] = 0ull; skey[3] = 0ull;
  }
  __syncthreads();
  float px[8], py[8], pz[8], dist[8];
  #pragma unroll
  for (int j = 0; j < 8; j++){
    int i = j * 512 + t;
    float4 v = xl4[i];
    px[j] = v.x; py[j] = v.y; pz[j] = v.z; dist[j] = 1e10f;
  }
  const unsigned a0 = 4095u - t;     // inv_j = a0 - j*512
  for (int s = 0; s < 1024; s++){
    const unsigned long long kg = skey[s & 3];
    const int far = 4095 - (int)(unsigned)(kg & 0xFFFFFFFFull);
    const float4 c4 = xl4[far];
    const float cx = c4.x, cy = c4.y, cz = c4.z;
    if (t == 0){
      farhist[s] = (unsigned short)far;
      skey[(s + 2) & 3] = 0ull;        // reset ring slot for step s+1's writers
    }
    float vm = -1.f;
    #pragma unroll
    for (int j = 0; j < 8; j++){
      float dx = __fsub_rn(px[j], cx), dy = __fsub_rn(py[j], cy), dz = __fsub_rn(pz[j], cz);
      float d = __fadd_rn(__fadd_rn(__fmul_rn(dx, dx), __fmul_rn(dy, dy)), __fmul_rn(dz, dz));
      float dm = fminf(dist[j], d); dist[j] = dm;
      vm = fmaxf(vm, dm);
    }
    const float wred = dppmax6(vm);
    const float wvm = __int_as_float(__builtin_amdgcn_readlane(__float_as_int(wred), 63));
    if (vm == wvm){                     // usually 1 lane/wave
      unsigned inv = 0u;
      #pragma unroll
      for (int j = 7; j >= 0; j--)
        if (dist[j] == wvm) inv = a0 - (unsigned)(j * 512);  // smallest j -> largest inv -> smallest idx
      atomicMax(&skey[(s + 1) & 3],
                (((unsigned long long)__float_as_uint(wvm)) << 32) | inv);
    }
    __syncthreads();
  }
  for (int s2 = t; s2 < 1024; s2 += 512){
    const int f = farhist[s2];
    const float4 c4 = xl4[f];
    out0[(b * 3 + 0) * 1024 + s2] = c4.x;
    out0[(b * 3 + 1) * 1024 + s2] = c4.y;
    out0[(b * 3 + 2) * 1024 + s2] = c4.z;
    float* nx = &new_xyz[(b * 1024 + s2) * 3];
    nx[0] = c4.x; nx[1] = c4.y; nx[2] = c4.z;
  }
}

// ---------------- kNN (blocks 0..4095, R8-proven core) + Q (blocks 4096..4111)
__global__ __launch_bounds__(256) void knn_k(const float* __restrict__ xyz,
    const float* __restrict__ new_xyz, int* __restrict__ knn,
    const unsigned short* __restrict__ Wb1, float* __restrict__ Q){
  const int bid = blockIdx.x;
  const int t = threadIdx.x;
  if (bid >= 4096){                    // Q[b][s][o] = W1b·new_xyz[s]
    const int b = bid - 4096;
    for (int i = t; i < 65536; i += 256){
      const int s = i >> 6, o = i & 63;
      const float* nx = &new_xyz[(b * 1024 + s) * 3];
      Q[((size_t)(b * 1024) + s) * 64 + o] =
        dot3(bf2f(Wb1[o * 96 + 64]), bf2f(Wb1[o * 96 + 65]), bf2f(Wb1[o * 96 + 66]),
             nx[0], nx[1], nx[2]);
    }
    return;
  }
  const int g = bid * 4 + (t >> 6);
  const int lane = t & 63;
  const int b = g >> 10, s = g & 1023;
  const float* xb = xyz + (size_t)b * 3 * 4096;
  const float* c = &new_xyz[(b * 1024 + s) * 3];
  const float cx = c[0], cy = c[1], cz = c[2];
  const float sqc = __fadd_rn(__fadd_rn(__fmul_rn(cx, cx), __fmul_rn(cy, cy)), __fmul_rn(cz, cz));
  float d[64];
  float m1 = 3e38f, m2 = 3e38f, m3 = 3e38f, m4 = 3e38f;
  int i1 = 0x7fffffff, i2 = 0x7fffffff, i3 = 0x7fffffff, i4 = 0x7fffffff;
  #pragma unroll
  for (int j = 0; j < 64; j++){
    int i = j * 64 + lane;
    float x = xb[i], y = xb[4096 + i], z = xb[8192 + i];
    float sqn = __fadd_rn(__fadd_rn(__fmul_rn(x, x), __fmul_rn(y, y)), __fmul_rn(z, z));
    float dot = __fadd_rn(__fadd_rn(__fmul_rn(cx, x), __fmul_rn(cy, y)), __fmul_rn(cz, z));
    float dd = __fsub_rn(__fadd_rn(sqc, sqn), __fmul_rn(2.0f, dot));
    d[j] = dd;
    bool c1 = dd < m1, c2 = dd < m2, c3 = dd < m3, c4 = dd < m4;
    m4 = c4 ? (c3 ? m3 : dd) : m4;  i4 = c4 ? (c3 ? i3 : i) : i4;
    m3 = c3 ? (c2 ? m2 : dd) : m3;  i3 = c3 ? (c2 ? i2 : i) : i3;
    m2 = c2 ? (c1 ? m1 : dd) : m2;  i2 = c2 ? (c1 ? i1 : i) : i2;
    m1 = c1 ? dd : m1;              i1 = c1 ? i : i1;
  }
  unsigned long long taken = 0ull;
  int out_idx = 0;
  #pragma unroll 1
  for (int r = 0; r < 32; r++){
    const float gred = dppmin6(m1);
    const float gmin = __int_as_float(__builtin_amdgcn_readlane(__float_as_int(gred), 63));
    const bool cand = (m1 == gmin);
    const unsigned long long cm = __ballot(cand);
    int widx;
    if (__popcll(cm) == 1){
      widx = __builtin_amdgcn_readlane(i1, (int)(__ffsll(cm) - 1));
    } else {                            // exact-tie rare path: min index among candidates
      unsigned ci = cand ? (unsigned)i1 : 0xFFFFFFFFu;
      widx = (int)__builtin_amdgcn_readlane((int)dppminu6(ci), 63);
    }
    if (lane == r) out_idx = widx;
    if (i1 == widx){                    // unique owner pops
      taken |= 1ull << (widx >> 6);
      m1 = m2; i1 = i2; m2 = m3; i2 = i3; m3 = m4; i3 = i4;
      m4 = 3e38f; i4 = 0x7fffffff;
      if (i1 == 0x7fffffff){            // spares exhausted (rare): refill top-4
        m1 = 3e38f; m2 = 3e38f; m3 = 3e38f; m4 = 3e38f;
        i1 = 0x7fffffff; i2 = 0x7fffffff; i3 = 0x7fffffff; i4 = 0x7fffffff;
        #pragma unroll
        for (int j = 0; j < 64; j++){
          if (!((taken >> j) & 1ull)){
            float dd = d[j]; int i = j * 64 + lane;
            bool c1 = dd < m1, c2 = dd < m2, c3 = dd < m3, c4 = dd < m4;
            m4 = c4 ? (c3 ? m3 : dd) : m4;  i4 = c4 ? (c3 ? i3 : i) : i4;
            m3 = c3 ? (c2 ? m2 : dd) : m3;  i3 = c3 ? (c2 ? i2 : i) : i3;
            m2 = c2 ? (c1 ? m1 : dd) : m2;  i2 = c2 ? (c1 ? i1 : i) : i2;
            m1 = c1 ? dd : m1;              i1 = c1 ? i : i1;
          }
        }
      }
    }
  }
  if (lane < 32) knn[((size_t)(b * 1024 + s)) * 32 + lane] = out_idx;
}

// ---------------- stats over z1 = P[idx]-Q[s] (layer-1 BN; z1 never stored)
__global__ __launch_bounds__(256) void stats1g_k(const float* __restrict__ P,
    const float* __restrict__ Q, const int* __restrict__ knn, float* __restrict__ stats){
  __shared__ float sb[4][2][64];
  const int t = threadIdx.x, bid = blockIdx.x;
  const int b = bid >> 7, colbase = (bid & 127) * 256;
  const int w = t >> 6, lane = t & 63;
  const int cw = colbase + w * 64;
  const int* kp = knn + (size_t)b * 32768 + cw;
  const float* Pb = P + (size_t)b * 4096 * 64;
  const int s0 = cw >> 5;
  const float qa = Q[((size_t)(b * 1024) + s0) * 64 + lane];
  const float qb = Q[((size_t)(b * 1024) + s0 + 1) * 64 + lane];
  float sm = 0.f, sq = 0.f;
  #pragma unroll 4
  for (int i = 0; i < 32; i++){
    const int idx = kp[i];
    const float v = Pb[(size_t)idx * 64 + lane] - qa;
    sm += v; sq += v * v;
  }
  #pragma unroll 4
  for (int i = 32; i < 64; i++){
    const int idx = kp[i];
    const float v = Pb[(size_t)idx * 64 + lane] - qb;
    sm += v; sq += v * v;
  }
  sb[w][0][lane] = sm; sb[w][1][lane] = sq;
  __syncthreads();
  if (t < 128){
    const int ch = t >> 1, q = t & 1;
    const float v = sb[0][q][ch] + sb[1][q][ch] + sb[2][q][ch] + sb[3][q][ch];
    atomicAdd(&stats[(bid & 63) * 128 + ch * 2 + q], v);
  }
}

// GEMM2: x = relu(a1*(P[idx]-Q[s])+c1), 64->64
__global__ __launch_bounds__(256) void gemm2_k(const float* __restrict__ P,
    const float* __restrict__ Q, const int* __restrict__ knn,
    const unsigned short* __restrict__ Wb2, const float* __restrict__ b2, const float* __restrict__ p1,
    unsigned short* __restrict__ z2, float* __restrict__ stats){
  __shared__ unsigned short Xl[256 * XS];
  __shared__ float bsum[128];
  __shared__ float pa[64], pc[64];
  const int t = threadIdx.x, bid = blockIdx.x;
  const int b = bid >> 7, col0 = (bid & 127) * 256;
  if (t < 128) bsum[t] = 0.f;
  if (t < 64){ pa[t] = p1[t * 2]; pc[t] = p1[t * 2 + 1]; }
  const int lane = t & 63, lr = lane & 15, lg = lane >> 4;
  const int colw = (t >> 6) * 64;
  bfrag a[4][2];
  #pragma unroll
  for (int r = 0; r < 4; r++)
    #pragma unroll
    for (int kk = 0; kk < 2; kk++)
      a[r][kk] = *(const bfrag*)&Wb2[(16 * r + lr) * 64 + kk * 32 + lg * 8];
  __syncthreads();   // pa/pc ready
  {
    const int col = col0 + t;
    const int idx = knn[(size_t)b * 32768 + col];
    const int s = col >> 5;
    const float* Pr = P + ((size_t)(b * 4096) + idx) * 64;
    const float* Qr = Q + ((size_t)(b * 1024) + s) * 64;
    #pragma unroll
    for (int j = 0; j < 8; j++){
      ffrag pv0 = *(const ffrag*)&Pr[j * 8];
      ffrag pv1 = *(const ffrag*)&Pr[j * 8 + 4];
      ffrag qv0 = *(const ffrag*)&Qr[j * 8];
      ffrag qv1 = *(const ffrag*)&Qr[j * 8 + 4];
      unsigned short ov[8];
      #pragma unroll
      for (int e = 0; e < 4; e++){
        int ch = j * 8 + e;
        float v = fmaxf(fmaf(pa[ch], pv0[e] - qv0[e], pc[ch]), 0.f);
        ov[e] = f2bf(v);
      }
      #pragma unroll
      for (int e = 0; e < 4; e++){
        int ch = j * 8 + 4 + e;
        float v = fmaxf(fmaf(pa[ch], pv1[e] - qv1[e], pc[ch]), 0.f);
        ov[4 + e] = f2bf(v);
      }
      *(ushort8*)&Xl[t * XS + j * 8] = *(ushort8*)ov;
    }
  }
  __syncthreads();
  ffrag acc[4][4] = {};
  #pragma unroll
  for (int kk = 0; kk < 2; kk++){
    bfrag bb[4];
    #pragma unroll
    for (int cf = 0; cf < 4; cf++)
      bb[cf] = *(const bfrag*)&Xl[(colw + cf * 16 + lr) * XS + kk * 32 + lg * 8];
    #pragma unroll
    for (int r = 0; r < 4; r++)
      #pragma unroll
      for (int cf = 0; cf < 4; cf++)
        acc[r][cf] = __builtin_amdgcn_mfma_f32_16x16x32_bf16(a[r][kk], bb[cf], acc[r][cf], 0, 0, 0);
  }
  #pragma unroll
  for (int r = 0; r < 4; r++){
    const int o0 = 16 * r + 4 * lg;
    const ffrag bv = *(const ffrag*)&b2[o0];
    float sm[4] = {0,0,0,0}, sq[4] = {0,0,0,0};
    #pragma unroll
    for (int cf = 0; cf < 4; cf++){
      const int col = col0 + colw + cf * 16 + lr;
      unsigned pk[2];
      #pragma unroll
      for (int e = 0; e < 4; e++){
        float v = acc[r][cf][e] + bv[e];
        sm[e] += v; sq[e] += v * v;
        ((unsigned short*)pk)[e] = f2bf(v);
      }
      *(unsigned long long*)&z2[((size_t)(b * 32768) + col) * 64 + o0] = *(unsigned long long*)pk;
    }
    #pragma unroll
    for (int e = 0; e < 4; e++){
      float s1 = dppadd4(sm[e]);
      float q1 = dppadd4(sq[e]);
      if (lr == 0){ atomicAdd(&bsum[(o0 + e) * 2], s1); atomicAdd(&bsum[(o0 + e) * 2 + 1], q1); }
    }
  }
  __syncthreads();
  if (t < 128) atomicAdd(&stats[(bid & 63) * 128 + t], bsum[t]);
}

// GEMM3: 64->128, fused max/min over K (z3 never materialized)
__global__ __launch_bounds__(256) void gemm3_k(const unsigned short* __restrict__ z2,
    const unsigned short* __restrict__ Wb3, const float* __restrict__ b3, const float* __restrict__ p2,
    float* __restrict__ maxz, float* __restrict__ minz, float* __restrict__ stats){
  __shared__ unsigned short Xl[128 * XS];
  __shared__ float bsum[256];
  __shared__ float pa[64], pc[64];
  const int t = threadIdx.x, bid = blockIdx.x;
  const int b = bid >> 8, col0 = (bid & 255) * 128;
  bsum[t] = 0.f;
  if (t < 64){ pa[t] = p2[t * 2]; pc[t] = p2[t * 2 + 1]; }
  const int lane = t & 63, lr = lane & 15, lg = lane >> 4;
  const int w = t >> 6, wr = w >> 1, wc = w & 1;
  bfrag a[4][2];
  #pragma unroll
  for (int r = 0; r < 4; r++)
    #pragma unroll
    for (int kk = 0; kk < 2; kk++)
      a[r][kk] = *(const bfrag*)&Wb3[(wr * 64 + 16 * r + lr) * 64 + kk * 32 + lg * 8];
  __syncthreads();
  {
    const int colL = t & 127, half = t >> 7;
    const size_t gcol = (size_t)b * 32768 + col0 + colL;
    const unsigned short* src = z2 + gcol * 64 + half * 32;
    #pragma unroll
    for (int j = 0; j < 4; j++){
      ushort8 zv = *(const ushort8*)&src[j * 8];
      unsigned short ov[8];
      #pragma unroll
      for (int e = 0; e < 8; e++){
        int ch = half * 32 + j * 8 + e;
        float v = fmaxf(fmaf(pa[ch], bf2f(zv[e]), pc[ch]), 0.f);
        ov[e] = f2bf(v);
      }
      *(ushort8*)&Xl[colL * XS + half * 32 + j * 8] = *(ushort8*)ov;
    }
  }
  __syncthreads();
  ffrag acc[4][4] = {};
  #pragma unroll
  for (int kk = 0; kk < 2; kk++){
    bfrag bb[4];
    #pragma unroll
    for (int cf = 0; cf < 4; cf++)
      bb[cf] = *(const bfrag*)&Xl[(wc * 64 + cf * 16 + lr) * XS + kk * 32 + lg * 8];
    #pragma unroll
    for (int r = 0; r < 4; r++)
      #pragma unroll
      for (int cf = 0; cf < 4; cf++)
        acc[r][cf] = __builtin_amdgcn_mfma_f32_16x16x32_bf16(a[r][kk], bb[cf], acc[r][cf], 0, 0, 0);
  }
  const int s0 = (col0 + wc * 64) >> 5;    // 64 cols = 2 s values (K=32)
  #pragma unroll
  for (int r = 0; r < 4; r++){
    const int o0 = wr * 64 + 16 * r + 4 * lg;
    const ffrag bv = *(const ffrag*)&b3[(o0 & 127)];
    float vv[4][4];
    float sm[4] = {0,0,0,0}, sq[4] = {0,0,0,0};
    #pragma unroll
    for (int cf = 0; cf < 4; cf++)
      #pragma unroll
      for (int e = 0; e < 4; e++){
        float v = acc[r][cf][e] + bv[e];
        vv[cf][e] = v; sm[e] += v; sq[e] += v * v;
      }
    #pragma unroll
    for (int e = 0; e < 4; e++){
      float s1 = dppadd4(sm[e]);
      float q1 = dppadd4(sq[e]);
      if (lr == 0){ atomicAdd(&bsum[((o0 + e) & 127) * 2], s1); atomicAdd(&bsum[((o0 + e) & 127) * 2 + 1], q1); }
    }
    #pragma unroll
    for (int si = 0; si < 2; si++){
      ffrag mx, mn;
      #pragma unroll
      for (int e = 0; e < 4; e++){
        mx[e] = dppmax4(fmaxf(vv[si * 2][e], vv[si * 2 + 1][e]));
        mn[e] = dppmin4(fminf(vv[si * 2][e], vv[si * 2 + 1][e]));
      }
      if (lr == 0){
        *(ffrag*)&maxz[((size_t)(b * 1024) + s0 + si) * 128 + o0] = mx;
        *(ffrag*)&minz[((size_t)(b * 1024) + s0 + si) * 128 + o0] = mn;
      }
    }
  }
  __syncthreads();
  atomicAdd(&stats[(bid & 63) * 256 + t], bsum[t]);
}

// stats -> (a, c) affine params
template<int CH>
__global__ void stats_k(const float* __restrict__ stats, const float* __restrict__ gamma,
                        const float* __restrict__ beta, float* __restrict__ params){
  const int t = threadIdx.x;
  float sm = 0.f, sq = 0.f;
  for (int sl = 0; sl < 64; sl++){
    sm += stats[sl * (CH * 2) + t * 2];
    sq += stats[sl * (CH * 2) + t * 2 + 1];
  }
  const float cnt = 524288.f;
  float mean = sm / cnt;
  float var = sq / cnt - mean * mean;
  if (var < 0.f) var = 0.f;
  float inv = gamma[t] / sqrtf(var + 1e-5f);
  params[t * 2] = inv;
  params[t * 2 + 1] = beta[t] - mean * inv;
}

// final: out1[b][o][s] = relu(a3*sel+c3), LDS transpose for coalesced writes
__global__ __launch_bounds__(256) void final_k(const float* __restrict__ maxz,
    const float* __restrict__ minz, const float* __restrict__ p3, float* __restrict__ out1){
  __shared__ float tile[64][129];
  __shared__ float pa[128], pc[128];
  const int t = threadIdx.x, bid = blockIdx.x;
  const int b = bid >> 4, s0 = (bid & 15) * 64;
  if (t < 128){ pa[t] = p3[t * 2]; pc[t] = p3[t * 2 + 1]; }
  __syncthreads();
  const int o = t & 127, rr = t >> 7;
  for (int it = 0; it < 32; it++){
    int srow = it * 2 + rr;
    size_t base = ((size_t)(b * 1024) + s0 + srow) * 128 + o;
    float aa = pa[o], cc = pc[o];
    float m = (aa >= 0.f) ? maxz[base] : minz[base];
    tile[srow][o] = fmaxf(fmaf(aa, m, cc), 0.f);
  }
  __syncthreads();
  const int sc = t & 63, og = t >> 6;
  for (int it = 0; it < 32; it++){
    int o2 = it * 4 + og;
    out1[((size_t)(b * 128 + o2)) * 1024 + s0 + sc] = tile[sc][o2];
  }
}

extern "C" void kernel_launch(void* const* d_in, const int* in_sizes, int n_in,
                              void* d_out, int out_size, void* d_ws, size_t ws_size,
                              hipStream_t stream){
  const float* xyz = (const float*)d_in[0];
  const float* pts = (const float*)d_in[1];
  const float* W1 = (const float*)d_in[2];  const float* b1 = (const float*)d_in[3];
  const float* g1 = (const float*)d_in[4];  const float* be1 = (const float*)d_in[5];
  const float* W2 = (const float*)d_in[6];  const float* b2 = (const float*)d_in[7];
  const float* g2 = (const float*)d_in[8];  const float* be2 = (const float*)d_in[9];
  const float* W3 = (const float*)d_in[10]; const float* b3 = (const float*)d_in[11];
  const float* g3 = (const float*)d_in[12]; const float* be3 = (const float*)d_in[13];
  float* out0 = (float*)d_out;
  float* out1 = out0 + 16 * 3 * 1024;

  char* w = (char*)d_ws;
  size_t off = 0;
  auto alloc = [&](size_t bytes){ void* p = w + off; off = (off + bytes + 255) & ~(size_t)255; return p; };
  float* new_xyz        = (float*)alloc(196608);                 // [B][S][3]
  int*   knn            = (int*)alloc(2097152);                  // [B][S][32]
  float* P              = (float*)alloc(16777216);               // [B][N][64] f32
  float* Q              = (float*)alloc(4194304);                // [B][S][64] f32
  unsigned short* z2    = (unsigned short*)alloc(67108864);      // [B*S*K][64] bf16
  float* maxz           = (float*)alloc(8388608);                // [B][S][128]
  float* minz           = (float*)alloc(8388608);
  unsigned short* Wb1   = (unsigned short*)alloc(12288);         // [64][96] bf16
  unsigned short* Wb2   = (unsigned short*)alloc(8192);          // [64][64]
  unsigned short* Wb3   = (unsigned short*)alloc(16384);         // [128][64]
  float* stats          = (float*)alloc(131072);                 // s1[64][128], s2 same, s3[64][256]
  float* params         = (float*)alloc(2048);
  if (ws_size < off) return;

  float* stats1 = stats;            // 8192 floats
  float* stats2 = stats + 8192;     // 8192 floats
  float* stats3 = stats + 16384;    // 16384 floats
  float* p1 = params, *p2 = params + 128, *p3 = params + 256;

  wconv_k<<<1, 256, 0, stream>>>(W1, W2, W3, Wb1, Wb2, Wb3, stats);
  fused_fps_tr_k<<<272, 512, 0, stream>>>(xyz, pts, out0, new_xyz, Wb1, b1, P);
  knn_k<<<4112, 256, 0, stream>>>(xyz, new_xyz, knn, Wb1, Q);
  stats1g_k<<<2048, 256, 0, stream>>>(P, Q, knn, stats1);
  stats_k<64><<<1, 64, 0, stream>>>(stats1, g1, be1, p1);
  gemm2_k<<<2048, 256, 0, stream>>>(P, Q, knn, Wb2, b2, p1, z2, stats2);
  stats_k<64><<<1, 64, 0, stream>>>(stats2, g2, be2, p2);
  gemm3_k<<<4096, 256, 0, stream>>>(z2, Wb3, b3, p2, maxz, minz, stats3);
  stats_k<128><<<1, 128, 0, stream>>>(stats3, g3, be3, p3);
  final_k<<<256, 256, 0, stream>>>(maxz, minz, p3, out1);
}

// Round 14
// 750.824 us; speedup vs baseline: 1.4040x; 1.4040x over previous
//
#include <hip/hip_runtime.h>
#include <hip/hip_bf16.h>

// SetAbstraction: FPS -> kNN(32) -> gather -> 3x(conv1x1+BN+ReLU) -> maxpool(K)
// B=16 N=4096 S=1024 K=32 D_IN=64 MLP=[64,64,128]
// Structure: wconv | fused{fps + transpose + knn(spin-on-farr, hidden under fps)}
//            | gemm1 | stats | gemm2 | stats | gemm3 | stats | final

typedef __attribute__((ext_vector_type(8))) short bfrag;    // 8 bf16 (MFMA A/B)
typedef __attribute__((ext_vector_type(4))) float ffrag;    // 4 f32 (MFMA C/D)
typedef __attribute__((ext_vector_type(8))) unsigned short ushort8;

#define XS 104   // LDS row stride in bf16 elems: 16B-aligned, 2-way bank conflict (free)

__device__ inline unsigned short f2bf(float f){
  union { float f; unsigned u; } v; v.f = f;
  unsigned r = v.u + 0x7fffu + ((v.u >> 16) & 1u);   // RNE
  return (unsigned short)(r >> 16);
}
__device__ inline float bf2f(unsigned short h){
  union { unsigned u; float f; } v; v.u = ((unsigned)h) << 16; return v.f;
}

// ---- DPP cross-lane (VALU-rate; no LDS pipe)
template<int CTRL> __device__ __forceinline__ int dppi(int v){
  return __builtin_amdgcn_update_dpp(0, v, CTRL, 0xF, 0xF, true);
}
template<int CTRL> __device__ __forceinline__ float dppf(float v){
  return __int_as_float(dppi<CTRL>(__float_as_int(v)));
}
__device__ __forceinline__ float dppmax6(float v){   // lane63 = wave max
  v = fmaxf(v, dppf<0xB1>(v)); v = fmaxf(v, dppf<0x4E>(v));
  v = fmaxf(v, dppf<0x141>(v)); v = fmaxf(v, dppf<0x140>(v));
  v = fmaxf(v, dppf<0x142>(v)); v = fmaxf(v, dppf<0x143>(v));
  return v;
}
__device__ __forceinline__ float dppmin6(float v){   // lane63 = wave min
  v = fminf(v, dppf<0xB1>(v)); v = fminf(v, dppf<0x4E>(v));
  v = fminf(v, dppf<0x141>(v)); v = fminf(v, dppf<0x140>(v));
  v = fminf(v, dppf<0x142>(v)); v = fminf(v, dppf<0x143>(v));
  return v;
}
__device__ __forceinline__ unsigned dppminu6(unsigned v){
  unsigned o;
  o = (unsigned)dppi<0xB1>((int)v);  v = v < o ? v : o;
  o = (unsigned)dppi<0x4E>((int)v);  v = v < o ? v : o;
  o = (unsigned)dppi<0x141>((int)v); v = v < o ? v : o;
  o = (unsigned)dppi<0x140>((int)v); v = v < o ? v : o;
  o = (unsigned)dppi<0x142>((int)v); v = v < o ? v : o;
  o = (unsigned)dppi<0x143>((int)v); v = v < o ? v : o;
  return v;                                          // lane63 = wave min
}
__device__ __forceinline__ float dppadd4(float v){   // all lanes: 16-lane-row sum
  v += dppf<0xB1>(v); v += dppf<0x4E>(v); v += dppf<0x141>(v); v += dppf<0x140>(v);
  return v;
}
__device__ __forceinline__ float dppmax4(float v){
  v = fmaxf(v, dppf<0xB1>(v)); v = fmaxf(v, dppf<0x4E>(v));
  v = fmaxf(v, dppf<0x141>(v)); v = fmaxf(v, dppf<0x140>(v));
  return v;
}
__device__ __forceinline__ float dppmin4(float v){
  v = fminf(v, dppf<0xB1>(v)); v = fminf(v, dppf<0x4E>(v));
  v = fminf(v, dppf<0x141>(v)); v = fminf(v, dppf<0x140>(v));
  return v;
}

// ---------------- wconv: W -> bf16 (Wb1 padded 67->96) + zero stats + zero farr
__global__ __launch_bounds__(256) void wconv_k(const float* __restrict__ W1,
    const float* __restrict__ W2, const float* __restrict__ W3,
    unsigned short* __restrict__ Wb1, unsigned short* __restrict__ Wb2,
    unsigned short* __restrict__ Wb3, float* __restrict__ stats, int* __restrict__ farr){
  const int t = threadIdx.x;
  for (int i = t; i < 64 * 96; i += 256){
    int r = i / 96, c = i % 96;
    Wb1[i] = (c < 67) ? f2bf(W1[r * 67 + c]) : (unsigned short)0;
  }
  for (int i = t; i < 64 * 64; i += 256) Wb2[i] = f2bf(W2[i]);
  for (int i = t; i < 128 * 64; i += 256) Wb3[i] = f2bf(W3[i]);
  for (int i = t; i < 32768; i += 256) stats[i] = 0.f;
  for (int i = t; i < 16384; i += 256) farr[i] = 0;
}

// ---------------- mega-fused: FPS (blocks 0..15) + transpose (16..271) +
// kNN (272..2319, spin-waiting on farr progress; hidden under FPS).
// LDS padded to 96KB -> strictly 1 block/CU: fps CUs never host other blocks.
// FPS per step: t0 publishes farr[b*1024+s] = far+1 (global atomicExch,
// fire-and-forget); kNN wave for (b,s) spins until nonzero, reads centroid
// coords directly from xyz[far] (bit-identical to new_xyz values).
__global__ __launch_bounds__(512) void fused_k(const float* __restrict__ xyz,
    const float* __restrict__ pts, unsigned short* __restrict__ pts_t, float* __restrict__ xyz_t,
    float* __restrict__ out0, float* __restrict__ new_xyz,
    int* __restrict__ farr, int* __restrict__ knn){
  __shared__ __align__(16) char smem[98304];   // 96KB: forces 1 block/CU
  const int t = threadIdx.x, bid = blockIdx.x;
  if (bid >= 272){
    // ---------------- kNN path (8 waves/block, 1 centroid/wave, s-major) ----------------
    const int bid2 = bid - 272;
    const int w = t >> 6, lane = t & 63;
    const int b = bid2 & 15;
    const int s = (bid2 >> 4) * 8 + w;
    const float* xb = xyz + (size_t)b * 3 * 4096;
    int fidx;
    while ((fidx = atomicAdd(&farr[b * 1024 + s], 0)) == 0)
      __builtin_amdgcn_s_sleep(16);
    const int far = fidx - 1;
    const float cx = xb[far], cy = xb[4096 + far], cz = xb[8192 + far];
    const float sqc = __fadd_rn(__fadd_rn(__fmul_rn(cx, cx), __fmul_rn(cy, cy)), __fmul_rn(cz, cz));
    float d[64];
    float m1 = 3e38f, m2 = 3e38f, m3 = 3e38f, m4 = 3e38f;
    int i1 = 0x7fffffff, i2 = 0x7fffffff, i3 = 0x7fffffff, i4 = 0x7fffffff;
    #pragma unroll
    for (int j = 0; j < 64; j++){
      int i = j * 64 + lane;
      float x = xb[i], y = xb[4096 + i], z = xb[8192 + i];
      float sqn = __fadd_rn(__fadd_rn(__fmul_rn(x, x), __fmul_rn(y, y)), __fmul_rn(z, z));
      float dot = __fadd_rn(__fadd_rn(__fmul_rn(cx, x), __fmul_rn(cy, y)), __fmul_rn(cz, z));
      float dd = __fsub_rn(__fadd_rn(sqc, sqn), __fmul_rn(2.0f, dot));
      d[j] = dd;
      bool c1 = dd < m1, c2 = dd < m2, c3 = dd < m3, c4 = dd < m4;
      m4 = c4 ? (c3 ? m3 : dd) : m4;  i4 = c4 ? (c3 ? i3 : i) : i4;
      m3 = c3 ? (c2 ? m2 : dd) : m3;  i3 = c3 ? (c2 ? i2 : i) : i3;
      m2 = c2 ? (c1 ? m1 : dd) : m2;  i2 = c2 ? (c1 ? i1 : i) : i2;
      m1 = c1 ? dd : m1;              i1 = c1 ? i : i1;
    }
    unsigned long long taken = 0ull;
    int out_idx = 0;
    #pragma unroll 1
    for (int r = 0; r < 32; r++){
      const float gred = dppmin6(m1);
      const float gmin = __int_as_float(__builtin_amdgcn_readlane(__float_as_int(gred), 63));
      const bool cand = (m1 == gmin);
      const unsigned long long cm = __ballot(cand);
      int widx;
      if (__popcll(cm) == 1){
        widx = __builtin_amdgcn_readlane(i1, (int)(__ffsll(cm) - 1));
      } else {                            // exact-tie rare path: min index among candidates
        unsigned ci = cand ? (unsigned)i1 : 0xFFFFFFFFu;
        widx = (int)__builtin_amdgcn_readlane((int)dppminu6(ci), 63);
      }
      if (lane == r) out_idx = widx;
      if (i1 == widx){                    // unique owner pops
        taken |= 1ull << (widx >> 6);
        m1 = m2; i1 = i2; m2 = m3; i2 = i3; m3 = m4; i3 = i4;
        m4 = 3e38f; i4 = 0x7fffffff;
        if (i1 == 0x7fffffff){            // spares exhausted (rare): refill top-4
          m1 = 3e38f; m2 = 3e38f; m3 = 3e38f; m4 = 3e38f;
          i1 = 0x7fffffff; i2 = 0x7fffffff; i3 = 0x7fffffff; i4 = 0x7fffffff;
          #pragma unroll
          for (int j = 0; j < 64; j++){
            if (!((taken >> j) & 1ull)){
              float dd = d[j]; int i = j * 64 + lane;
              bool c1 = dd < m1, c2 = dd < m2, c3 = dd < m3, c4 = dd < m4;
              m4 = c4 ? (c3 ? m3 : dd) : m4;  i4 = c4 ? (c3 ? i3 : i) : i4;
              m3 = c3 ? (c2 ? m2 : dd) : m3;  i3 = c3 ? (c2 ? i2 : i) : i3;
              m2 = c2 ? (c1 ? m1 : dd) : m2;  i2 = c2 ? (c1 ? i1 : i) : i2;
              m1 = c1 ? dd : m1;              i1 = c1 ? i : i1;
            }
          }
        }
      }
    }
    if (lane < 32) knn[((size_t)(b * 1024 + s)) * 32 + lane] = out_idx;
    return;
  }
  if (bid >= 16){
    // ---------------- transpose path (512 thr) ----------------
    unsigned short* tile = (unsigned short*)smem;       // 64*258*2 = 33024 B
    const int bid2 = bid - 16;
    const int b = bid2 >> 4, n0 = (bid2 & 15) * 256;
    {
      const int n = t & 255, ch = t >> 8;               // ch in {0,1}
      for (int it = 0; it < 32; it++){
        int c = it * 2 + ch;
        tile[c * 258 + n] = f2bf(pts[((size_t)(b * 64 + c)) * 4096 + n0 + n]);
      }
    }
    __syncthreads();
    const int nn = t >> 5, c2 = (t & 31) * 2;           // nn 0..15
    for (int rep = 0; rep < 16; rep++){
      int n = rep * 16 + nn;
      unsigned lo = tile[c2 * 258 + n], hi = tile[(c2 + 1) * 258 + n];
      ((unsigned*)pts_t)[(((size_t)(b * 4096 + n0 + n)) * 64 + c2) >> 1] = lo | (hi << 16);
    }
    if (t < 256){
      float x = xyz[((size_t)(b * 3 + 0)) * 4096 + n0 + t];
      float y = xyz[((size_t)(b * 3 + 1)) * 4096 + n0 + t];
      float z = xyz[((size_t)(b * 3 + 2)) * 4096 + n0 + t];
      float* dst = &xyz_t[((size_t)(b * 4096 + n0 + t)) * 3];
      dst[0] = x; dst[1] = y; dst[2] = z;
    }
    return;
  }
  // ---------------- FPS path (512 thr, 8 pts/thr; R8-proven) ----------------
  float4* xl4 = (float4*)smem;                               // 65536 B
  unsigned long long* skey = (unsigned long long*)(smem + 65536);   // 32 B
  unsigned short* farhist = (unsigned short*)(smem + 65568);        // 2048 B
  const int b = bid;
  {
    const float* xb = xyz + (size_t)b * 3 * 4096;
    for (int j = 0; j < 8; j++){
      int i = j * 512 + t;
      float4 v; v.x = xb[i]; v.y = xb[4096 + i]; v.z = xb[8192 + i]; v.w = 0.f;
      xl4[i] = v;
    }
  }
  if (t == 0){
    skey[0] = 0xFFFFFFFF00000FFFull;   // lo=4095 -> far=0
    skey[1] = 0ull; skey[2] = 0ull; skey[3] = 0ull;
  }
  __syncthreads();
  float px[8], py[8], pz[8], dist[8];
  #pragma unroll
  for (int j = 0; j < 8; j++){
    int i = j * 512 + t;
    float4 v = xl4[i];
    px[j] = v.x; py[j] = v.y; pz[j] = v.z; dist[j] = 1e10f;
  }
  const unsigned a0 = 4095u - t;     // inv_j = a0 - j*512
  for (int s = 0; s < 1024; s++){
    const unsigned long long kg = skey[s & 3];
    const int far = 4095 - (int)(unsigned)(kg & 0xFFFFFFFFull);
    const float4 c4 = xl4[far];
    const float cx = c4.x, cy = c4.y, cz = c4.z;
    if (t == 0){
      farhist[s] = (unsigned short)far;
      skey[(s + 2) & 3] = 0ull;        // reset ring slot for step s+1's writers
      atomicExch(&farr[b * 1024 + s], far + 1);   // publish to kNN consumers
    }
    float vm = -1.f;
    #pragma unroll
    for (int j = 0; j < 8; j++){
      float dx = __fsub_rn(px[j], cx), dy = __fsub_rn(py[j], cy), dz = __fsub_rn(pz[j], cz);
      float d = __fadd_rn(__fadd_rn(__fmul_rn(dx, dx), __fmul_rn(dy, dy)), __fmul_rn(dz, dz));
      float dm = fminf(dist[j], d); dist[j] = dm;
      vm = fmaxf(vm, dm);
    }
    const float wred = dppmax6(vm);
    const float wvm = __int_as_float(__builtin_amdgcn_readlane(__float_as_int(wred), 63));
    if (vm == wvm){                     // usually 1 lane/wave
      unsigned inv = 0u;
      #pragma unroll
      for (int j = 7; j >= 0; j--)
        if (dist[j] == wvm) inv = a0 - (unsigned)(j * 512);  // smallest j -> largest inv -> smallest idx
      atomicMax(&skey[(s + 1) & 3],
                (((unsigned long long)__float_as_uint(wvm)) << 32) | inv);
    }
    __syncthreads();
  }
  for (int s2 = t; s2 < 1024; s2 += 512){
    const int f = farhist[s2];
    const float4 c4 = xl4[f];
    out0[(b * 3 + 0) * 1024 + s2] = c4.x;
    out0[(b * 3 + 1) * 1024 + s2] = c4.y;
    out0[(b * 3 + 2) * 1024 + s2] = c4.z;
    float* nx = &new_xyz[(b * 1024 + s2) * 3];
    nx[0] = c4.x; nx[1] = c4.y; nx[2] = c4.z;
  }
}

// ---------------- MFMA GEMMs. D layout (16x16x32): col = lane&15, row = (lane>>4)*4 + reg

// GEMM1: gather(67ch) -> z1 bf16 [col][64] + stats
__global__ __launch_bounds__(256) void gemm1_k(const unsigned short* __restrict__ pts_t,
    const float* __restrict__ xyz_t, const float* __restrict__ new_xyz,
    const int* __restrict__ knn, const unsigned short* __restrict__ Wb1, const float* __restrict__ b1,
    unsigned short* __restrict__ z1, float* __restrict__ stats){
  __shared__ unsigned short Xl[256 * XS];
  __shared__ float bsum[128];
  const int t = threadIdx.x, bid = blockIdx.x;
  const int b = bid >> 7, col0 = (bid & 127) * 256;
  if (t < 128) bsum[t] = 0.f;
  {
    const int col = col0 + t, s = col >> 5, k = col & 31;
    const int idx = knn[((size_t)(b * 1024 + s)) * 32 + k];
    const unsigned short* src = pts_t + ((size_t)(b * 4096 + idx)) * 64;
    #pragma unroll
    for (int j = 0; j < 8; j++) *(ushort8*)&Xl[t * XS + j * 8] = *(const ushort8*)&src[j * 8];
    const float* nx = &new_xyz[(b * 1024 + s) * 3];
    const float* gx = &xyz_t[((size_t)(b * 4096 + idx)) * 3];
    ushort8 tail = {0,0,0,0,0,0,0,0};
    tail[0] = f2bf(__fsub_rn(gx[0], nx[0]));
    tail[1] = f2bf(__fsub_rn(gx[1], nx[1]));
    tail[2] = f2bf(__fsub_rn(gx[2], nx[2]));
    *(ushort8*)&Xl[t * XS + 64] = tail;
    ushort8 zz8 = {0,0,0,0,0,0,0,0};
    *(ushort8*)&Xl[t * XS + 72] = zz8;
    *(ushort8*)&Xl[t * XS + 80] = zz8;
    *(ushort8*)&Xl[t * XS + 88] = zz8;
  }
  const int lane = t & 63, lr = lane & 15, lg = lane >> 4;
  const int colw = (t >> 6) * 64;
  bfrag a[4][3];
  #pragma unroll
  for (int r = 0; r < 4; r++)
    #pragma unroll
    for (int kk = 0; kk < 3; kk++)
      a[r][kk] = *(const bfrag*)&Wb1[(16 * r + lr) * 96 + kk * 32 + lg * 8];
  __syncthreads();
  ffrag acc[4][4] = {};
  #pragma unroll
  for (int kk = 0; kk < 3; kk++){
    bfrag bb[4];
    #pragma unroll
    for (int cf = 0; cf < 4; cf++)
      bb[cf] = *(const bfrag*)&Xl[(colw + cf * 16 + lr) * XS + kk * 32 + lg * 8];
    #pragma unroll
    for (int r = 0; r < 4; r++)
      #pragma unroll
      for (int cf = 0; cf < 4; cf++)
        acc[r][cf] = __builtin_amdgcn_mfma_f32_16x16x32_bf16(a[r][kk], bb[cf], acc[r][cf], 0, 0, 0);
  }
  #pragma unroll
  for (int r = 0; r < 4; r++){
    const int o0 = 16 * r + 4 * lg;
    const ffrag bv = *(const ffrag*)&b1[o0];
    float sm[4] = {0,0,0,0}, sq[4] = {0,0,0,0};
    #pragma unroll
    for (int cf = 0; cf < 4; cf++){
      const int col = col0 + colw + cf * 16 + lr;
      unsigned pk[2];
      #pragma unroll
      for (int e = 0; e < 4; e++){
        float v = acc[r][cf][e] + bv[e];
        sm[e] += v; sq[e] += v * v;
        ((unsigned short*)pk)[e] = f2bf(v);
      }
      *(unsigned long long*)&z1[((size_t)(b * 32768) + col) * 64 + o0] = *(unsigned long long*)pk;
    }
    #pragma unroll
    for (int e = 0; e < 4; e++){
      float s1 = dppadd4(sm[e]);
      float q1 = dppadd4(sq[e]);
      if (lr == 0){ atomicAdd(&bsum[(o0 + e) * 2], s1); atomicAdd(&bsum[(o0 + e) * 2 + 1], q1); }
    }
  }
  __syncthreads();
  if (t < 128) atomicAdd(&stats[(bid & 63) * 128 + t], bsum[t]);
}

// GEMM2: x = relu(a1*z1+c1), 64->64
__global__ __launch_bounds__(256) void gemm2_k(const unsigned short* __restrict__ z1,
    const unsigned short* __restrict__ Wb2, const float* __restrict__ b2, const float* __restrict__ p1,
    unsigned short* __restrict__ z2, float* __restrict__ stats){
  __shared__ unsigned short Xl[256 * XS];
  __shared__ float bsum[128];
  __shared__ float pa[64], pc[64];
  const int t = threadIdx.x, bid = blockIdx.x;
  const int b = bid >> 7, col0 = (bid & 127) * 256;
  if (t < 128) bsum[t] = 0.f;
  if (t < 64){ pa[t] = p1[t * 2]; pc[t] = p1[t * 2 + 1]; }
  const int lane = t & 63, lr = lane & 15, lg = lane >> 4;
  const int colw = (t >> 6) * 64;
  bfrag a[4][2];
  #pragma unroll
  for (int r = 0; r < 4; r++)
    #pragma unroll
    for (int kk = 0; kk < 2; kk++)
      a[r][kk] = *(const bfrag*)&Wb2[(16 * r + lr) * 64 + kk * 32 + lg * 8];
  __syncthreads();   // pa/pc ready
  {
    const size_t gcol = (size_t)b * 32768 + col0 + t;
    const unsigned short* src = z1 + gcol * 64;
    #pragma unroll
    for (int j = 0; j < 8; j++){
      ushort8 zv = *(const ushort8*)&src[j * 8];
      unsigned short ov[8];
      #pragma unroll
      for (int e = 0; e < 8; e++){
        int ch = j * 8 + e;
        float v = fmaxf(fmaf(pa[ch], bf2f(zv[e]), pc[ch]), 0.f);
        ov[e] = f2bf(v);
      }
      *(ushort8*)&Xl[t * XS + j * 8] = *(ushort8*)ov;
    }
  }
  __syncthreads();
  ffrag acc[4][4] = {};
  #pragma unroll
  for (int kk = 0; kk < 2; kk++){
    bfrag bb[4];
    #pragma unroll
    for (int cf = 0; cf < 4; cf++)
      bb[cf] = *(const bfrag*)&Xl[(colw + cf * 16 + lr) * XS + kk * 32 + lg * 8];
    #pragma unroll
    for (int r = 0; r < 4; r++)
      #pragma unroll
      for (int cf = 0; cf < 4; cf++)
        acc[r][cf] = __builtin_amdgcn_mfma_f32_16x16x32_bf16(a[r][kk], bb[cf], acc[r][cf], 0, 0, 0);
  }
  #pragma unroll
  for (int r = 0; r < 4; r++){
    const int o0 = 16 * r + 4 * lg;
    const ffrag bv = *(const ffrag*)&b2[o0];
    float sm[4] = {0,0,0,0}, sq[4] = {0,0,0,0};
    #pragma unroll
    for (int cf = 0; cf < 4; cf++){
      const int col = col0 + colw + cf * 16 + lr;
      unsigned pk[2];
      #pragma unroll
      for (int e = 0; e < 4; e++){
        float v = acc[r][cf][e] + bv[e];
        sm[e] += v; sq[e] += v * v;
        ((unsigned short*)pk)[e] = f2bf(v);
      }
      *(unsigned long long*)&z2[((size_t)(b * 32768) + col) * 64 + o0] = *(unsigned long long*)pk;
    }
    #pragma unroll
    for (int e = 0; e < 4; e++){
      float s1 = dppadd4(sm[e]);
      float q1 = dppadd4(sq[e]);
      if (lr == 0){ atomicAdd(&bsum[(o0 + e) * 2], s1); atomicAdd(&bsum[(o0 + e) * 2 + 1], q1); }
    }
  }
  __syncthreads();
  if (t < 128) atomicAdd(&stats[(bid & 63) * 128 + t], bsum[t]);
}

// GEMM3: 64->128, fused max/min over K (z3 never materialized)
__global__ __launch_bounds__(256) void gemm3_k(const unsigned short* __restrict__ z2,
    const unsigned short* __restrict__ Wb3, const float* __restrict__ b3, const float* __restrict__ p2,
    float* __restrict__ maxz, float* __restrict__ minz, float* __restrict__ stats){
  __shared__ unsigned short Xl[128 * XS];
  __shared__ float bsum[256];
  __shared__ float pa[64], pc[64];
  const int t = threadIdx.x, bid = blockIdx.x;
  const int b = bid >> 8, col0 = (bid & 255) * 128;
  bsum[t] = 0.f;
  if (t < 64){ pa[t] = p2[t * 2]; pc[t] = p2[t * 2 + 1]; }
  const int lane = t & 63, lr = lane & 15, lg = lane >> 4;
  const int w = t >> 6, wr = w >> 1, wc = w & 1;
  bfrag a[4][2];
  #pragma unroll
  for (int r = 0; r < 4; r++)
    #pragma unroll
    for (int kk = 0; kk < 2; kk++)
      a[r][kk] = *(const bfrag*)&Wb3[(wr * 64 + 16 * r + lr) * 64 + kk * 32 + lg * 8];
  __syncthreads();
  {
    const int colL = t & 127, half = t >> 7;
    const size_t gcol = (size_t)b * 32768 + col0 + colL;
    const unsigned short* src = z2 + gcol * 64 + half * 32;
    #pragma unroll
    for (int j = 0; j < 4; j++){
      ushort8 zv = *(const ushort8*)&src[j * 8];
      unsigned short ov[8];
      #pragma unroll
      for (int e = 0; e < 8; e++){
        int ch = half * 32 + j * 8 + e;
        float v = fmaxf(fmaf(pa[ch], bf2f(zv[e]), pc[ch]), 0.f);
        ov[e] = f2bf(v);
      }
      *(ushort8*)&Xl[colL * XS + half * 32 + j * 8] = *(ushort8*)ov;
    }
  }
  __syncthreads();
  ffrag acc[4][4] = {};
  #pragma unroll
  for (int kk = 0; kk < 2; kk++){
    bfrag bb[4];
    #pragma unroll
    for (int cf = 0; cf < 4; cf++)
      bb[cf] = *(const bfrag*)&Xl[(wc * 64 + cf * 16 + lr) * XS + kk * 32 + lg * 8];
    #pragma unroll
    for (int r = 0; r < 4; r++)
      #pragma unroll
      for (int cf = 0; cf < 4; cf++)
        acc[r][cf] = __builtin_amdgcn_mfma_f32_16x16x32_bf16(a[r][kk], bb[cf], acc[r][cf], 0, 0, 0);
  }
  const int s0 = (col0 + wc * 64) >> 5;    // 64 cols = 2 s values (K=32)
  #pragma unroll
  for (int r = 0; r < 4; r++){
    const int o0 = wr * 64 + 16 * r + 4 * lg;
    const ffrag bv = *(const ffrag*)&b3[(o0 & 127)];
    float vv[4][4];
    float sm[4] = {0,0,0,0}, sq[4] = {0,0,0,0};
    #pragma unroll
    for (int cf = 0; cf < 4; cf++)
      #pragma unroll
      for (int e = 0; e < 4; e++){
        float v = acc[r][cf][e] + bv[e];
        vv[cf][e] = v; sm[e] += v; sq[e] += v * v;
      }
    #pragma unroll
    for (int e = 0; e < 4; e++){
      float s1 = dppadd4(sm[e]);
      float q1 = dppadd4(sq[e]);
      if (lr == 0){ atomicAdd(&bsum[((o0 + e) & 127) * 2], s1); atomicAdd(&bsum[((o0 + e) & 127) * 2 + 1], q1); }
    }
    #pragma unroll
    for (int si = 0; si < 2; si++){
      ffrag mx, mn;
      #pragma unroll
      for (int e = 0; e < 4; e++){
        mx[e] = dppmax4(fmaxf(vv[si * 2][e], vv[si * 2 + 1][e]));
        mn[e] = dppmin4(fminf(vv[si * 2][e], vv[si * 2 + 1][e]));
      }
      if (lr == 0){
        *(ffrag*)&maxz[((size_t)(b * 1024) + s0 + si) * 128 + o0] = mx;
        *(ffrag*)&minz[((size_t)(b * 1024) + s0 + si) * 128 + o0] = mn;
      }
    }
  }
  __syncthreads();
  atomicAdd(&stats[(bid & 63) * 256 + t], bsum[t]);
}

// stats -> (a, c) affine params
template<int CH>
__global__ void stats_k(const float* __restrict__ stats, const float* __restrict__ gamma,
                        const float* __restrict__ beta, float* __restrict__ params){
  const int t = threadIdx.x;
  float sm = 0.f, sq = 0.f;
  for (int sl = 0; sl < 64; sl++){
    sm += stats[sl * (CH * 2) + t * 2];
    sq += stats[sl * (CH * 2) + t * 2 + 1];
  }
  const float cnt = 524288.f;
  float mean = sm / cnt;
  float var = sq / cnt - mean * mean;
  if (var < 0.f) var = 0.f;
  float inv = gamma[t] / sqrtf(var + 1e-5f);
  params[t * 2] = inv;
  params[t * 2 + 1] = beta[t] - mean * inv;
}

// final: out1[b][o][s] = relu(a3*sel+c3), LDS transpose for coalesced writes
__global__ __launch_bounds__(256) void final_k(const float* __restrict__ maxz,
    const float* __restrict__ minz, const float* __restrict__ p3, float* __restrict__ out1){
  __shared__ float tile[64][129];
  __shared__ float pa[128], pc[128];
  const int t = threadIdx.x, bid = blockIdx.x;
  const int b = bid >> 4, s0 = (bid & 15) * 64;
  if (t < 128){ pa[t] = p3[t * 2]; pc[t] = p3[t * 2 + 1]; }
  __syncthreads();
  const int o = t & 127, rr = t >> 7;
  for (int it = 0; it < 32; it++){
    int srow = it * 2 + rr;
    size_t base = ((size_t)(b * 1024) + s0 + srow) * 128 + o;
    float aa = pa[o], cc = pc[o];
    float m = (aa >= 0.f) ? maxz[base] : minz[base];
    tile[srow][o] = fmaxf(fmaf(aa, m, cc), 0.f);
  }
  __syncthreads();
  const int sc = t & 63, og = t >> 6;
  for (int it = 0; it < 32; it++){
    int o2 = it * 4 + og;
    out1[((size_t)(b * 128 + o2)) * 1024 + s0 + sc] = tile[sc][o2];
  }
}

extern "C" void kernel_launch(void* const* d_in, const int* in_sizes, int n_in,
                              void* d_out, int out_size, void* d_ws, size_t ws_size,
                              hipStream_t stream){
  const float* xyz = (const float*)d_in[0];
  const float* pts = (const float*)d_in[1];
  const float* W1 = (const float*)d_in[2];  const float* b1 = (const float*)d_in[3];
  const float* g1 = (const float*)d_in[4];  const float* be1 = (const float*)d_in[5];
  const float* W2 = (const float*)d_in[6];  const float* b2 = (const float*)d_in[7];
  const float* g2 = (const float*)d_in[8];  const float* be2 = (const float*)d_in[9];
  const float* W3 = (const float*)d_in[10]; const float* b3 = (const float*)d_in[11];
  const float* g3 = (const float*)d_in[12]; const float* be3 = (const float*)d_in[13];
  float* out0 = (float*)d_out;
  float* out1 = out0 + 16 * 3 * 1024;

  char* w = (char*)d_ws;
  size_t off = 0;
  auto alloc = [&](size_t bytes){ void* p = w + off; off = (off + bytes + 255) & ~(size_t)255; return p; };
  unsigned short* pts_t = (unsigned short*)alloc(8388608);      // [B][N][64] bf16
  float* xyz_t          = (float*)alloc(786432);                 // [B][N][3]
  float* new_xyz        = (float*)alloc(196608);                 // [B][S][3]
  int*   knn            = (int*)alloc(2097152);                  // [B][S][32]
  unsigned short* z1    = (unsigned short*)alloc(67108864);      // [B*S*K][64] bf16
  unsigned short* z2    = (unsigned short*)alloc(67108864);
  float* maxz           = (float*)alloc(8388608);                // [B][S][128]
  float* minz           = (float*)alloc(8388608);
  unsigned short* Wb1   = (unsigned short*)alloc(12288);         // [64][96] bf16
  unsigned short* Wb2   = (unsigned short*)alloc(8192);          // [64][64]
  unsigned short* Wb3   = (unsigned short*)alloc(16384);         // [128][64]
  float* stats          = (float*)alloc(131072);                 // s1[64][128], s2 same, s3[64][256]
  float* params         = (float*)alloc(2048);
  int*   farr           = (int*)alloc(65536);                    // [B][S] progress (far+1)
  if (ws_size < off) return;

  float* stats1 = stats;            // 8192 floats
  float* stats2 = stats + 8192;     // 8192 floats
  float* stats3 = stats + 16384;    // 16384 floats
  float* p1 = params, *p2 = params + 128, *p3 = params + 256;

  wconv_k<<<1, 256, 0, stream>>>(W1, W2, W3, Wb1, Wb2, Wb3, stats, farr);
  fused_k<<<2320, 512, 0, stream>>>(xyz, pts, pts_t, xyz_t, out0, new_xyz, farr, knn);
  gemm1_k<<<2048, 256, 0, stream>>>(pts_t, xyz_t, new_xyz, knn, Wb1, b1, z1, stats1);
  stats_k<64><<<1, 64, 0, stream>>>(stats1, g1, be1, p1);
  gemm2_k<<<2048, 256, 0, stream>>>(z1, Wb2, b2, p1, z2, stats2);
  stats_k<64><<<1, 64, 0, stream>>>(stats2, g2, be2, p2);
  gemm3_k<<<4096, 256, 0, stream>>>(z2, Wb3, b3, p2, maxz, minz, stats3);
  stats_k<128><<<1, 128, 0, stream>>>(stats3, g3, be3, p3);
  final_k<<<256, 256, 0, stream>>>(maxz, minz, p3, out1);
}